// Round 8
// baseline (354.409 us; speedup 1.0000x reference)
//
#include <hip/hip_runtime.h>

// Problem constants: B=16, DIM(C)=512, N=4096, H=8, HD=64, QKV rows = 8*129 = 1032.
#define NB 16
#define NC 512
#define NN 4096
#define NH 8

typedef __attribute__((ext_vector_type(8))) __bf16 bf16x8;
typedef __attribute__((ext_vector_type(4))) float f32x4;

__device__ __forceinline__ unsigned short f2bf(float f) {
    union { float f; unsigned u; } x; x.f = f;
    unsigned r = x.u + 0x7FFF + ((x.u >> 16) & 1);   // round-to-nearest-even
    return (unsigned short)(r >> 16);
}

// K0: repack Wv rows (head-interleaved) + Wp to bf16, gather bv.
__global__ void pack_kernel(const float* __restrict__ Wqkv, const float* __restrict__ bqkv,
                            const float* __restrict__ Wp,
                            unsigned short* __restrict__ Wv_bf, unsigned short* __restrict__ Wp_bf,
                            float* __restrict__ bv) {
    int t = blockIdx.x * 256 + threadIdx.x;          // 0 .. 512*512-1
    int j = t >> 9, c = t & 511;
    int h = j >> 6, d = j & 63;
    Wv_bf[t] = f2bf(Wqkv[((size_t)h * 129 + 65 + d) * 512 + c]);
    Wp_bf[t] = f2bf(Wp[t]);
    if (t < 512) bv[t] = bqkv[(t >> 6) * 129 + 65 + (t & 63)];
}

// K1: q c-chunk partials qP[cc][b][h][n] (fp32 exact; bias dropped: softmax shift-inv).
__global__ __launch_bounds__(256) void q_kernel(
        const float* __restrict__ x, const float* __restrict__ Wqkv,
        float* __restrict__ qP) {
    __shared__ float Ws[8][64];
    int n0 = blockIdx.x * 512, c0 = blockIdx.y * 64, b = blockIdx.z;
    int t = threadIdx.x;                             // 256
    for (int i = t; i < 512; i += 256)
        Ws[i >> 6][i & 63] = Wqkv[(size_t)(i >> 6) * (129 * 512) + c0 + (i & 63)];
    __syncthreads();

    float acc[8][2];
#pragma unroll
    for (int h = 0; h < 8; h++) { acc[h][0] = 0.f; acc[h][1] = 0.f; }

    const float* xb = x + ((size_t)b * NC + c0) * NN + n0;
#pragma unroll 4
    for (int c = 0; c < 64; c++) {
        float2 v = *((const float2*)(xb + (size_t)c * NN) + t);
#pragma unroll
        for (int h = 0; h < 8; h++) {
            float w = Ws[h][c];
            acc[h][0] += w * v.x;
            acc[h][1] += w * v.y;
        }
    }
#pragma unroll
    for (int h = 0; h < 8; h++) {
        float2 o; o.x = acc[h][0]; o.y = acc[h][1];
        *((float2*)(qP + ((size_t)(blockIdx.y * NB + b) * 8 + h) * NN + n0) + t) = o;
    }
}

// K2: softmax over N per (b,h) of q = sum of 8 c-chunk partials -> sT[b][n][h].
__global__ void softmax_kernel(const float* __restrict__ qP, float* __restrict__ sT) {
    int bh = blockIdx.x;                 // b*8+h
    int b = bh >> 3, h = bh & 7;
    int t = threadIdx.x;                 // 256
    __shared__ float red[8];
    const float* qp = qP + (size_t)bh * NN;
    const size_t cstr = (size_t)NB * 8 * NN;
    float v[16];
    float mx = -1e30f;
#pragma unroll
    for (int i = 0; i < 16; i++) {
        int n = t + i * 256;
        float s = 0.f;
#pragma unroll
        for (int cb = 0; cb < 8; cb++) s += qp[cb * cstr + n];
        v[i] = s; mx = fmaxf(mx, s);
    }
#pragma unroll
    for (int o = 32; o; o >>= 1) mx = fmaxf(mx, __shfl_xor(mx, o));
    if ((t & 63) == 0) red[t >> 6] = mx;
    __syncthreads();
    mx = fmaxf(fmaxf(red[0], red[1]), fmaxf(red[2], red[3]));
    float s = 0.f;
#pragma unroll
    for (int i = 0; i < 16; i++) { v[i] = __expf(v[i] - mx); s += v[i]; }
#pragma unroll
    for (int o = 32; o; o >>= 1) s += __shfl_xor(s, o);
    __syncthreads();
    if ((t & 63) == 0) red[4 + (t >> 6)] = s;
    __syncthreads();
    float inv = 1.f / (red[4] + red[5] + red[6] + red[7]);
#pragma unroll
    for (int i = 0; i < 16; i++) {
        int n = t + i * 256;
        sT[((size_t)b * NN + n) * 8 + h] = v[i] * inv;
    }
}

// K3: partial xbar[slab][b][h][c] = sum_{n in 512-slab} sT[b][n][h] * x[b,c,n]
__global__ __launch_bounds__(256) void xbar_kernel(
        const float* __restrict__ x, const float* __restrict__ sT,
        float* __restrict__ xbarP) {
    __shared__ float red[4][8][64];
    int c0 = blockIdx.x * 32, sl = blockIdx.y, b = blockIdx.z;
    int t = threadIdx.x;
    int l = t & 63, w = t >> 6;
    int nsl0 = sl * 512;
    float s_[8][8];
    {
        const f32x4* sp = (const f32x4*)(sT + ((size_t)b * NN + nsl0 + l * 8) * 8);
#pragma unroll
        for (int j = 0; j < 8; j++) {
            f32x4 a = sp[2 * j], bq = sp[2 * j + 1];
            s_[j][0] = a[0]; s_[j][1] = a[1]; s_[j][2] = a[2]; s_[j][3] = a[3];
            s_[j][4] = bq[0]; s_[j][5] = bq[1]; s_[j][6] = bq[2]; s_[j][7] = bq[3];
        }
    }
    float acc[8][8];
#pragma unroll
    for (int r = 0; r < 8; r++)
#pragma unroll
        for (int h = 0; h < 8; h++) acc[r][h] = 0.f;

    const float* xr = x + ((size_t)b * NC + c0 + w * 8) * NN + nsl0 + l * 8;
#pragma unroll
    for (int r = 0; r < 8; r++) {
        float4 a0 = *(const float4*)(xr + (size_t)r * NN);
        float4 a1 = *(const float4*)(xr + (size_t)r * NN + 4);
        float xf[8] = {a0.x, a0.y, a0.z, a0.w, a1.x, a1.y, a1.z, a1.w};
#pragma unroll
        for (int j = 0; j < 8; j++)
#pragma unroll
            for (int h = 0; h < 8; h++) acc[r][h] += xf[j] * s_[j][h];
    }
#pragma unroll
    for (int r = 0; r < 8; r++)
#pragma unroll
        for (int h = 0; h < 8; h++) {
            float a = acc[r][h];
            a += __shfl_xor(a, 8);
            a += __shfl_xor(a, 16);
            a += __shfl_xor(a, 32);
            acc[r][h] = a;
        }
    if (l < 8) {
#pragma unroll
        for (int r = 0; r < 8; r++)
#pragma unroll
            for (int h = 0; h < 8; h++) red[w][l][r * 8 + h] = acc[r][h];
    }
    __syncthreads();
    {
        int idx = t & 63;
        float v = 0.f;
#pragma unroll
        for (int res = 0; res < 8; res++) v += red[w][res][idx];
        int r = idx >> 3, h = idx & 7;
        xbarP[(((size_t)sl * NB + b) * 8 + h) * NC + c0 + w * 8 + r] = v;
    }
}

// K4: ctx[b][h*64+d] = Wk[h,d,:].xbar[b,h,:] + bk[h,d]
__global__ void ctx_kernel(const float* __restrict__ xbarP, const float* __restrict__ Wqkv,
                           const float* __restrict__ bqkv, float* __restrict__ ctx) {
    int bh = blockIdx.x; int b = bh >> 3, h = bh & 7;
    int t = threadIdx.x;                                    // 256
    __shared__ float xb[512];
    for (int i = t; i < 512; i += 256) {
        float s = 0.f;
#pragma unroll
        for (int sl = 0; sl < 8; sl++) s += xbarP[(((size_t)sl * NB + b) * 8 + h) * NC + i];
        xb[i] = s;
    }
    __syncthreads();
    int d = t >> 2, sub = t & 3;
    const float* wk = Wqkv + ((size_t)h * 129 + 1 + d) * 512;
    float acc = 0.f;
    for (int i = sub * 4; i < 512; i += 16) {
        float4 w = *(const float4*)(wk + i);
        acc += w.x * xb[i] + w.y * xb[i + 1] + w.z * xb[i + 2] + w.w * xb[i + 3];
    }
    acc += __shfl_xor(acc, 1);
    acc += __shfl_xor(acc, 2);
    if (sub == 0) ctx[(size_t)b * NC + h * 64 + d] = acc + bqkv[h * 129 + 1 + d];
}

// K5: FUSED double GEMM per (b, 64-n tile). BN=64, BK=64, 8 waves (4 wj x 2 wn),
// wave tile 128j x 32n (acc = 64 VGPR). All LDS tiles: 128B rows, G4 swizzle
// byte ^= (row&7)<<4 -> 2-way (free) on 16-lane column reads.
//   phase A: M[512][64] = relu(Wv.x + bv).ctx ; x staged fp32->bf16, dbuf, 1 barrier/kstep
//   phase B: out[512][64] = Wp.M + bp ; barrier-free (Ms + register A-frags)
__global__ __launch_bounds__(512, 2) void fused_gemm_kernel(
    const unsigned short* __restrict__ Wv,    // [512][512] bf16
    const unsigned short* __restrict__ Wp,    // [512][512] bf16
    const float* __restrict__ x,              // [B][512][4096] fp32
    const float* __restrict__ bv,
    const float* __restrict__ bp,
    const float* __restrict__ ctx,            // [B][512]
    float* __restrict__ outp)                 // [B][512][4096] fp32
{
    __shared__ alignas(16) unsigned short Ms[8 * 64 * 64];   // 64 KB  [kt][n][64k]
    __shared__ alignas(16) unsigned short Xs[2][64 * 64];    // 2x8 KB [n][64c]
    int b = blockIdx.y, n0 = blockIdx.x * 64;
    int t = threadIdx.x;
    int lane = t & 63, wid = t >> 6;
    int wj = wid >> 1, wn = wid & 1;
    int g = lane >> 4, col = lane & 15;
    int k8 = g * 8;

    // staging coords: c-pair base 2*cp, n quad n4..n4+3
    int cp = t >> 4, n4 = (t & 15) * 4;

    f32x4 acc[8][2];
#pragma unroll
    for (int i = 0; i < 8; i++) { f32x4 z = {0.f,0.f,0.f,0.f}; acc[i][0] = z; acc[i][1] = z; }

    // prologue: load kstep 0
    float4 sv0, sv1;
    {
        const float* xr = x + ((size_t)b * NC + 2 * cp) * NN + n0 + n4;
        sv0 = *(const float4*)(xr);
        sv1 = *(const float4*)(xr + NN);
    }

    // ---------------- phase A ----------------
    for (int k = 0; k < 8; k++) {
        int kk = k * 64;
        // write staged regs (for THIS kstep) into Xs[k&1]
        {
            unsigned short* base = Xs[k & 1];
            unsigned w0 = (unsigned)f2bf(sv0.x) | ((unsigned)f2bf(sv1.x) << 16);
            unsigned w1 = (unsigned)f2bf(sv0.y) | ((unsigned)f2bf(sv1.y) << 16);
            unsigned w2 = (unsigned)f2bf(sv0.z) | ((unsigned)f2bf(sv1.z) << 16);
            unsigned w3 = (unsigned)f2bf(sv0.w) | ((unsigned)f2bf(sv1.w) << 16);
            *(unsigned*)((char*)base + (n4 + 0) * 128 + ((4 * cp) ^ (((n4 + 0) & 7) << 4))) = w0;
            *(unsigned*)((char*)base + (n4 + 1) * 128 + ((4 * cp) ^ (((n4 + 1) & 7) << 4))) = w1;
            *(unsigned*)((char*)base + (n4 + 2) * 128 + ((4 * cp) ^ (((n4 + 2) & 7) << 4))) = w2;
            *(unsigned*)((char*)base + (n4 + 3) * 128 + ((4 * cp) ^ (((n4 + 3) & 7) << 4))) = w3;
        }
        __syncthreads();
        // issue next kstep's global loads (hidden under MFMA below)
        if (k < 7) {
            const float* xr = x + ((size_t)b * NC + kk + 64 + 2 * cp) * NN + n0 + n4;
            sv0 = *(const float4*)(xr);
            sv1 = *(const float4*)(xr + NN);
        }
        const char* xsb = (const char*)Xs[k & 1];
        bf16x8 bfr[2][2];
#pragma unroll
        for (int n2 = 0; n2 < 2; n2++)
#pragma unroll
            for (int h = 0; h < 2; h++) {
                int row = wn * 32 + n2 * 16 + col;
                bfr[n2][h] = *(const bf16x8*)(xsb + row * 128 + ((2 * (h * 32 + k8)) ^ ((row & 7) << 4)));
            }
#pragma unroll
        for (int i = 0; i < 8; i++) {
            const unsigned short* ar = Wv + (size_t)(wj * 128 + i * 16 + col) * 512 + kk + k8;
            bf16x8 af0 = *(const bf16x8*)(ar);
            bf16x8 af1 = *(const bf16x8*)(ar + 32);
            acc[i][0] = __builtin_amdgcn_mfma_f32_16x16x32_bf16(af0, bfr[0][0], acc[i][0], 0, 0, 0);
            acc[i][1] = __builtin_amdgcn_mfma_f32_16x16x32_bf16(af0, bfr[1][0], acc[i][1], 0, 0, 0);
            acc[i][0] = __builtin_amdgcn_mfma_f32_16x16x32_bf16(af1, bfr[0][1], acc[i][0], 0, 0, 0);
            acc[i][1] = __builtin_amdgcn_mfma_f32_16x16x32_bf16(af1, bfr[1][1], acc[i][1], 0, 0, 0);
        }
        __syncthreads();
    }

    // phase A epilogue: relu(acc+bv)*ctx -> bf16 -> Ms[j>>6][n][j&63] (swizzled)
#pragma unroll
    for (int i = 0; i < 8; i++) {
        int j0 = wj * 128 + i * 16 + g * 4;
        float4 bv4 = *(const float4*)(bv + j0);
        float4 cx4 = *(const float4*)(ctx + (size_t)b * NC + j0);
#pragma unroll
        for (int n2 = 0; n2 < 2; n2++) {
            int n = wn * 32 + n2 * 16 + col;
            f32x4 a = acc[i][n2];
            unsigned short h0 = f2bf(fmaxf(a[0] + bv4.x, 0.f) * cx4.x);
            unsigned short h1 = f2bf(fmaxf(a[1] + bv4.y, 0.f) * cx4.y);
            unsigned short h2 = f2bf(fmaxf(a[2] + bv4.z, 0.f) * cx4.z);
            unsigned short h3 = f2bf(fmaxf(a[3] + bv4.w, 0.f) * cx4.w);
            uint2 pk;
            pk.x = (unsigned)h0 | ((unsigned)h1 << 16);
            pk.y = (unsigned)h2 | ((unsigned)h3 << 16);
            *(uint2*)((char*)Ms + (j0 >> 6) * 8192 + n * 128 + ((2 * (j0 & 63)) ^ ((n & 7) << 4))) = pk;
        }
    }
    __syncthreads();

    // ---------------- phase B (barrier-free) ----------------
#pragma unroll
    for (int i = 0; i < 8; i++) { f32x4 z = {0.f,0.f,0.f,0.f}; acc[i][0] = z; acc[i][1] = z; }

#pragma unroll 2
    for (int k = 0; k < 8; k++) {
        int kk = k * 64;
        const char* msb = (const char*)Ms + k * 8192;
        bf16x8 bfr[2][2];
#pragma unroll
        for (int n2 = 0; n2 < 2; n2++)
#pragma unroll
            for (int h = 0; h < 2; h++) {
                int row = wn * 32 + n2 * 16 + col;
                bfr[n2][h] = *(const bf16x8*)(msb + row * 128 + ((2 * (h * 32 + k8)) ^ ((row & 7) << 4)));
            }
#pragma unroll
        for (int i = 0; i < 8; i++) {
            const unsigned short* ar = Wp + (size_t)(wj * 128 + i * 16 + col) * 512 + kk + k8;
            bf16x8 af0 = *(const bf16x8*)(ar);
            bf16x8 af1 = *(const bf16x8*)(ar + 32);
            acc[i][0] = __builtin_amdgcn_mfma_f32_16x16x32_bf16(af0, bfr[0][0], acc[i][0], 0, 0, 0);
            acc[i][1] = __builtin_amdgcn_mfma_f32_16x16x32_bf16(af0, bfr[1][0], acc[i][1], 0, 0, 0);
            acc[i][0] = __builtin_amdgcn_mfma_f32_16x16x32_bf16(af1, bfr[0][1], acc[i][0], 0, 0, 0);
            acc[i][1] = __builtin_amdgcn_mfma_f32_16x16x32_bf16(af1, bfr[1][1], acc[i][1], 0, 0, 0);
        }
    }

    // phase B epilogue: out = acc + bp (fp32)
#pragma unroll
    for (int i = 0; i < 8; i++) {
        int o0 = wj * 128 + i * 16 + g * 4;
        float4 bp4 = *(const float4*)(bp + o0);
#pragma unroll
        for (int n2 = 0; n2 < 2; n2++) {
            int n = n0 + wn * 32 + n2 * 16 + col;
            f32x4 a = acc[i][n2];
            float* op = outp + ((size_t)b * NC + o0) * NN + n;
            op[0]              = a[0] + bp4.x;
            op[NN]             = a[1] + bp4.y;
            op[2 * (size_t)NN] = a[2] + bp4.z;
            op[3 * (size_t)NN] = a[3] + bp4.w;
        }
    }
}

extern "C" void kernel_launch(void* const* d_in, const int* in_sizes, int n_in,
                              void* d_out, int out_size, void* d_ws, size_t ws_size,
                              hipStream_t stream) {
    const float* x    = (const float*)d_in[0];
    const float* Wqkv = (const float*)d_in[1];
    const float* bqkv = (const float*)d_in[2];
    const float* Wp   = (const float*)d_in[3];
    const float* bp   = (const float*)d_in[4];
    float* outp = (float*)d_out;

    char* ws = (char*)d_ws;
    float* sT    = (float*)(ws);                                      // 2 MB
    float* qP    = (float*)(ws + 2097152);                            // 16 MB
    float* xbarP = (float*)(ws + 18874368);                           // 2 MB
    float* ctx   = (float*)(ws + 20971520);                           // 32 KB
    unsigned short* Wv_bf = (unsigned short*)(ws + 20971520 + 32768);            // 512 KB
    unsigned short* Wp_bf = (unsigned short*)(ws + 20971520 + 32768 + 524288);   // 512 KB
    float* bv    = (float*)(ws + 20971520 + 32768 + 1048576);         // 2 KB

    pack_kernel<<<dim3(1024), 256, 0, stream>>>(Wqkv, bqkv, Wp, Wv_bf, Wp_bf, bv);
    q_kernel<<<dim3(8, 8, 16), 256, 0, stream>>>(x, Wqkv, qP);
    softmax_kernel<<<dim3(128), 256, 0, stream>>>(qP, sT);
    xbar_kernel<<<dim3(16, 8, 16), 256, 0, stream>>>(x, sT, xbarP);
    ctx_kernel<<<dim3(128), 256, 0, stream>>>(xbarP, Wqkv, bqkv, ctx);
    fused_gemm_kernel<<<dim3(64, 16), 512, 0, stream>>>(Wv_bf, Wp_bf, x, bv, bp, ctx, outp);
}

// Round 9
// 230.858 us; speedup vs baseline: 1.5352x; 1.5352x over previous
//
#include <hip/hip_runtime.h>

// Problem constants: B=16, DIM(C)=512, N=4096, H=8, HD=64, QKV rows = 8*129 = 1032.
#define NB 16
#define NC 512
#define NN 4096
#define NH 8

typedef __attribute__((ext_vector_type(8))) __bf16 bf16x8;
typedef __attribute__((ext_vector_type(4))) float f32x4;

__device__ __forceinline__ unsigned short f2bf(float f) {
    union { float f; unsigned u; } x; x.f = f;
    unsigned r = x.u + 0x7FFF + ((x.u >> 16) & 1);   // round-to-nearest-even
    return (unsigned short)(r >> 16);
}
__device__ __forceinline__ float bits2f(unsigned u) {
    union { unsigned u; float f; } x; x.u = u; return x.f;
}

// async global->LDS 16B per lane; LDS dest must be wave-uniform base (HW adds lane*16).
__device__ __forceinline__ void async16(const void* g, const void* l) {
    __builtin_amdgcn_global_load_lds(
        (const __attribute__((address_space(1))) void*)g,
        (__attribute__((address_space(3))) void*)l, 16, 0, 0);
}

// K0: repack Wv rows (head-interleaved) + Wp to bf16, gather bv.
__global__ void pack_kernel(const float* __restrict__ Wqkv, const float* __restrict__ bqkv,
                            const float* __restrict__ Wp,
                            unsigned short* __restrict__ Wv_bf, unsigned short* __restrict__ Wp_bf,
                            float* __restrict__ bv) {
    int t = blockIdx.x * 256 + threadIdx.x;          // 0 .. 512*512-1
    int j = t >> 9, c = t & 511;
    int h = j >> 6, d = j & 63;
    Wv_bf[t] = f2bf(Wqkv[((size_t)h * 129 + 65 + d) * 512 + c]);
    Wp_bf[t] = f2bf(Wp[t]);
    if (t < 512) bv[t] = bqkv[(t >> 6) * 129 + 65 + (t & 63)];
}

// K1: fused transpose + q.  Block = (b, 32-n slab); TWO c-passes over a half tile.
// LDS 38KB -> 4 blocks/CU (R2 version was 55KB -> 2 blocks/CU, latency-bound).
//   x [b][c][n] fp32  ->  xT [b][n][c] bf16
//   q [b][h][n] = sum_c Wq[h,c] * x[b,c,n]   (fp32 exact, bias dropped: softmax shift-inv)
__global__ __launch_bounds__(256) void transpose_q_kernel(
        const float* __restrict__ x, const float* __restrict__ Wqkv,
        unsigned short* __restrict__ xT, float* __restrict__ q) {
    __shared__ unsigned int tile[256 * 17];          // 17.4 KB; pad 17 (coprime 32)
    __shared__ float Ws[8][512];                     // 16 KB
    __shared__ float qw[4][8][32];                   // 4 KB
    int b = blockIdx.y, n0 = blockIdx.x * 32;
    int t = threadIdx.x;                             // 256
    int lane = t & 63, wv = t >> 6;

    for (int i = t; i < 4096; i += 256)
        Ws[i >> 9][i & 511] = Wqkv[(size_t)(i >> 9) * (129 * 512) + (i & 511)];
    __syncthreads();

    int k = t & 7;                                   // n-quad: n = 4k..4k+3
    int r0 = t >> 3;                                 // 0..31
    float accq[8][4];
#pragma unroll
    for (int h = 0; h < 8; h++)
#pragma unroll
        for (int j = 0; j < 4; j++) accq[h][j] = 0.f;

    const float* xp = x + (size_t)b * NC * NN + n0 + 4 * k;
    unsigned short* xb = xT + (size_t)b * NN * NC;

    for (int pass = 0; pass < 2; pass++) {
        int cb = pass * 256;
        // Phase 1: read x (coalesced 128B per c-row), pack->LDS, accumulate q partials.
#pragma unroll
        for (int p = 0; p < 8; p++) {
            int cl = r0 + 32 * p;
            int c = cb + cl;
            float4 v = *(const float4*)(xp + (size_t)c * NN);
            tile[cl * 17 + 2 * k]     = (unsigned)f2bf(v.x) | ((unsigned)f2bf(v.y) << 16);
            tile[cl * 17 + 2 * k + 1] = (unsigned)f2bf(v.z) | ((unsigned)f2bf(v.w) << 16);
#pragma unroll
            for (int h = 0; h < 8; h++) {
                float w = Ws[h][c];
                accq[h][0] += w * v.x;
                accq[h][1] += w * v.y;
                accq[h][2] += w * v.z;
                accq[h][3] += w * v.w;
            }
        }
        __syncthreads();
        // Phase 2: transpose out this c-half. lane = c (stride-17 u32: conflict-free),
        // 128B-contiguous u16 stores.
        for (int it = wv; it < 64; it += 4) {
            int cw = it >> 4, np = it & 15;
            int cl = cw * 64 + lane;
            unsigned u = tile[cl * 17 + np];
            int n = n0 + 2 * np;
            xb[(size_t)n * NC + cb + cl]       = (unsigned short)(u & 0xFFFFu);
            xb[(size_t)(n + 1) * NC + cb + cl] = (unsigned short)(u >> 16);
        }
        __syncthreads();
    }

    // q reduce: lanes sharing k (lane&7) differ in lane bits 3..5 = c-subset -> xor 8/16/32
#pragma unroll
    for (int h = 0; h < 8; h++)
#pragma unroll
        for (int j = 0; j < 4; j++) {
            float a = accq[h][j];
            a += __shfl_xor(a, 8);
            a += __shfl_xor(a, 16);
            a += __shfl_xor(a, 32);
            accq[h][j] = a;
        }
    if (lane < 8) {
#pragma unroll
        for (int h = 0; h < 8; h++)
#pragma unroll
            for (int j = 0; j < 4; j++) qw[wv][h][4 * lane + j] = accq[h][j];
    }
    __syncthreads();
    {
        int h = t >> 5, n = t & 31;
        q[((size_t)b * 8 + h) * NN + n0 + n] =
            qw[0][h][n] + qw[1][h][n] + qw[2][h][n] + qw[3][h][n];
    }
}

// K2: softmax over N per (b,h); writes TRANSPOSED scores sT[b][n][h] (fp32).
__global__ void softmax_kernel(const float* __restrict__ q, float* __restrict__ sT) {
    int bh = blockIdx.x;                 // b*8+h
    int b = bh >> 3, h = bh & 7;
    int t = threadIdx.x;                 // 256
    __shared__ float red[8];
    const float* qp = q + (size_t)bh * NN;
    float v[16];
    float mx = -1e30f;
#pragma unroll
    for (int i = 0; i < 16; i++) { v[i] = qp[t + i * 256]; mx = fmaxf(mx, v[i]); }
#pragma unroll
    for (int o = 32; o; o >>= 1) mx = fmaxf(mx, __shfl_xor(mx, o));
    if ((t & 63) == 0) red[t >> 6] = mx;
    __syncthreads();
    mx = fmaxf(fmaxf(red[0], red[1]), fmaxf(red[2], red[3]));
    float s = 0.f;
#pragma unroll
    for (int i = 0; i < 16; i++) { v[i] = __expf(v[i] - mx); s += v[i]; }
#pragma unroll
    for (int o = 32; o; o >>= 1) s += __shfl_xor(s, o);
    __syncthreads();
    if ((t & 63) == 0) red[4 + (t >> 6)] = s;
    __syncthreads();
    float inv = 1.f / (red[4] + red[5] + red[6] + red[7]);
#pragma unroll
    for (int i = 0; i < 16; i++) {
        int n = t + i * 256;
        sT[((size_t)b * NN + n) * 8 + h] = v[i] * inv;
    }
}

// K3: partial xbar[sl64][b][h][c] = sum_{n in 64-slice} sT[b][n][h] * xT[b][n][c]
__global__ void xbar_kernel(const unsigned short* __restrict__ xT, const float* __restrict__ sT,
                            float* __restrict__ xbarP) {
    int b = blockIdx.y, sl = blockIdx.x;                 // 16 slices of 256 n
    int t = threadIdx.x;
    int g = __builtin_amdgcn_readfirstlane(t >> 6);      // wave id (uniform)
    int lane = t & 63;
    int c8 = lane * 8;
    int nbase = sl * 256 + g * 64;
    float acc[8][8];
#pragma unroll
    for (int h = 0; h < 8; h++)
#pragma unroll
        for (int c = 0; c < 8; c++) acc[h][c] = 0.f;
    const unsigned short* xp = xT + ((size_t)b * NN + nbase) * NC + c8;
    const float* sp = sT + ((size_t)b * NN + nbase) * 8;
    for (int i = 0; i < 64; i++) {
        uint4 xv = *(const uint4*)(xp + (size_t)i * NC);
        float xf[8];
        xf[0] = bits2f(xv.x << 16); xf[1] = bits2f(xv.x & 0xFFFF0000u);
        xf[2] = bits2f(xv.y << 16); xf[3] = bits2f(xv.y & 0xFFFF0000u);
        xf[4] = bits2f(xv.z << 16); xf[5] = bits2f(xv.z & 0xFFFF0000u);
        xf[6] = bits2f(xv.w << 16); xf[7] = bits2f(xv.w & 0xFFFF0000u);
#pragma unroll
        for (int h = 0; h < 8; h++) {
            float s = sp[i * 8 + h];
#pragma unroll
            for (int c = 0; c < 8; c++) acc[h][c] += s * xf[c];
        }
    }
#pragma unroll
    for (int h = 0; h < 8; h++) {
        float* dst = xbarP + (((size_t)(sl * 4 + g) * NB + b) * 8 + h) * NC + c8;
        f32x4 lo = {acc[h][0], acc[h][1], acc[h][2], acc[h][3]};
        f32x4 hi = {acc[h][4], acc[h][5], acc[h][6], acc[h][7]};
        *(f32x4*)(dst) = lo;
        *(f32x4*)(dst + 4) = hi;
    }
}

// K4: ctx[b][h*64+d] = Wk[h,d,:].xbar[b,h,:] + bk[h,d]   (sums 64 partial slices)
__global__ void ctx_kernel(const float* __restrict__ xbarP, const float* __restrict__ Wqkv,
                           const float* __restrict__ bqkv, float* __restrict__ ctx) {
    int bh = blockIdx.x; int b = bh >> 3, h = bh & 7;
    int t = threadIdx.x;                                    // 256
    __shared__ float xb[512];
    for (int i = t; i < 512; i += 256) {
        float s = 0.f;
        for (int sl = 0; sl < 64; sl++) s += xbarP[(((size_t)sl * NB + b) * 8 + h) * NC + i];
        xb[i] = s;
    }
    __syncthreads();
    int d = t >> 2, sub = t & 3;
    const float* wk = Wqkv + ((size_t)h * 129 + 1 + d) * 512;
    float acc = 0.f;
    for (int i = sub * 4; i < 512; i += 16) {
        float4 w = *(const float4*)(wk + i);
        acc += w.x * xb[i] + w.y * xb[i + 1] + w.z * xb[i + 2] + w.w * xb[i + 3];
    }
    acc += __shfl_xor(acc, 1);
    acc += __shfl_xor(acc, 2);
    if (sub == 0) ctx[(size_t)b * NC + h * 64 + d] = acc + bqkv[h * 129 + 1 + d];
}

// K5/K6: C[512 x 4096] = A[512x512] * B^T  (B stored as [n][k] bf16 rows), per batch.
// Staging via global_load_lds width=16 (m97 pattern): per wave, 3 async 1KB chunks.
// MODE 0: epilogue relu(acc+bv)*ctx -> bf16 -> LDS-staged COALESCED mT[b][n][j] writes.
// MODE 1: epilogue acc+bp -> fp32 out[b][o][n].
template <int MODE>
__global__ __launch_bounds__(512) void gemm_kernel(
    const unsigned short* __restrict__ A,     // [512][512] bf16 row-major
    const unsigned short* __restrict__ Bmat,  // [B][4096][512] bf16
    const float* __restrict__ bias,           // bv or bp
    const float* __restrict__ ctx,            // [B][512] (MODE 0)
    unsigned short* __restrict__ mT,          // MODE 0 output
    float* __restrict__ outp)                 // MODE 1 output
{
    __shared__ alignas(16) char smem[16384 + 8192];       // As 16KB | Bs 8KB (Es reuses)
    unsigned short* As = (unsigned short*)smem;           // [m 256][k 32] linear
    unsigned short* Bs = (unsigned short*)(smem + 16384); // [n 128][k 32] linear
    int b = blockIdx.z;
    int m0 = blockIdx.y * 256, n0 = blockIdx.x * 128;
    int t = threadIdx.x;
    int lane = t & 63;
    int wid = t >> 6;                                     // 8 waves
    int wm = wid >> 1, wn = wid & 1;                      // 4x2 wave grid, 64x64 per wave

    const unsigned short* Bb = Bmat + ((size_t)b * NN + n0) * NC;

    // per-lane source offsets for async staging (16B each; dest = wave base + lane*16)
    int srow = lane >> 2, sc8 = (lane & 3) * 8;

    f32x4 acc[4][4];
#pragma unroll
    for (int i = 0; i < 4; i++)
#pragma unroll
        for (int j = 0; j < 4; j++) { f32x4 z = {0.f, 0.f, 0.f, 0.f}; acc[i][j] = z; }

    for (int kk = 0; kk < 512; kk += 32) {
        // A rows [wid*32, wid*32+32): two 1KB chunks; B rows [wid*16, wid*16+16): one.
        async16(A + (size_t)(m0 + wid * 32 + srow) * 512 + kk + sc8,      As + wid * 1024);
        async16(A + (size_t)(m0 + wid * 32 + 16 + srow) * 512 + kk + sc8, As + wid * 1024 + 512);
        async16(Bb + (size_t)(wid * 16 + srow) * 512 + kk + sc8,          Bs + wid * 512);
        __syncthreads();                                  // drains vmcnt before barrier
        bf16x8 af[4], bfr[4];
        int koff = (lane >> 4) * 8;
        int arow = wm * 64 + (lane & 15);
        int brow = wn * 64 + (lane & 15);
#pragma unroll
        for (int i = 0; i < 4; i++) af[i]  = *(const bf16x8*)(As + (size_t)(arow + i * 16) * 32 + koff);
#pragma unroll
        for (int j = 0; j < 4; j++) bfr[j] = *(const bf16x8*)(Bs + (size_t)(brow + j * 16) * 32 + koff);
#pragma unroll
        for (int i = 0; i < 4; i++)
#pragma unroll
            for (int j = 0; j < 4; j++)
                acc[i][j] = __builtin_amdgcn_mfma_f32_16x16x32_bf16(af[i], bfr[j], acc[i][j], 0, 0, 0);
        __syncthreads();
    }

    // epilogue; D frag: col = lane&15, row = (lane>>4)*4 + reg
    int g = lane >> 4, col = lane & 15;
    if (MODE == 0) {
        // LDS-staged coalesced mT writes. 8 chunks of 16 n x 256 j (bf16).
        // Es row pitch 1032B (=258 words, %32=2) spreads banks.
        char* Es = smem;
#pragma unroll
        for (int ch = 0; ch < 8; ch++) {
            if (wn == (ch >> 2)) {
                constexpr int dummy = 0; (void)dummy;
#pragma unroll
                for (int i = 0; i < 4; i++) {
                    int jrel = wm * 64 + i * 16 + g * 4;
                    int j0 = m0 + jrel;
                    float4 bv4 = *(const float4*)(bias + j0);
                    float4 cx4 = *(const float4*)(ctx + (size_t)b * NC + j0);
                    f32x4 a = acc[i][ch & 3];
                    unsigned short h0 = f2bf(fmaxf(a[0] + bv4.x, 0.f) * cx4.x);
                    unsigned short h1 = f2bf(fmaxf(a[1] + bv4.y, 0.f) * cx4.y);
                    unsigned short h2 = f2bf(fmaxf(a[2] + bv4.z, 0.f) * cx4.z);
                    unsigned short h3 = f2bf(fmaxf(a[3] + bv4.w, 0.f) * cx4.w);
                    uint2 pk;
                    pk.x = (unsigned)h0 | ((unsigned)h1 << 16);
                    pk.y = (unsigned)h2 | ((unsigned)h3 << 16);
                    *(uint2*)(Es + col * 1032 + jrel * 2) = pk;
                }
            }
            __syncthreads();
            {
                int nl = t >> 5, jseg = t & 31;           // 16 n-rows x 32 16B-segments
                uint4 v = *(const uint4*)(Es + nl * 1032 + jseg * 16);
                int n = n0 + ch * 16 + nl;
                *(uint4*)(mT + ((size_t)b * NN + n) * NC + m0 + jseg * 8) = v;
            }
            __syncthreads();
        }
    } else {
#pragma unroll
        for (int i = 0; i < 4; i++) {
            int j0 = m0 + wm * 64 + i * 16 + g * 4;       // 4 consecutive output rows
            float4 bp4 = *(const float4*)(bias + j0);
#pragma unroll
            for (int j = 0; j < 4; j++) {
                int n = n0 + wn * 64 + j * 16 + col;
                f32x4 a = acc[i][j];
                float* op = outp + (size_t)b * NC * NN + (size_t)j0 * NN + n;
                op[0]              = a[0] + bp4.x;
                op[NN]             = a[1] + bp4.y;
                op[2 * (size_t)NN] = a[2] + bp4.z;
                op[3 * (size_t)NN] = a[3] + bp4.w;
            }
        }
    }
}

extern "C" void kernel_launch(void* const* d_in, const int* in_sizes, int n_in,
                              void* d_out, int out_size, void* d_ws, size_t ws_size,
                              hipStream_t stream) {
    const float* x    = (const float*)d_in[0];
    const float* Wqkv = (const float*)d_in[1];
    const float* bqkv = (const float*)d_in[2];
    const float* Wp   = (const float*)d_in[3];
    const float* bp   = (const float*)d_in[4];
    float* outp = (float*)d_out;

    // ws layout. mT occupies [0, 64MB). sT/q/xbarP overlap mT's range but are
    // fully consumed (K1..K4) before K5 writes mT. ctx/Wv/Wp/bv live past 64MB.
    char* ws = (char*)d_ws;
    unsigned short* mT = (unsigned short*)ws;                         // 64 MB
    float* sT    = (float*)(ws + 2097152);                            // [2MB,4MB)
    float* q     = (float*)(ws + 4194304);                            // [4MB,6MB)
    float* xbarP = (float*)(ws + 20971520);                           // [20MB,36MB)
    float* ctx   = (float*)(ws + 67108864);                           // 32 KB
    unsigned short* Wv_bf = (unsigned short*)(ws + 67108864 + 32768);            // 512 KB
    unsigned short* Wp_bf = (unsigned short*)(ws + 67108864 + 32768 + 524288);   // 512 KB
    float* bv    = (float*)(ws + 67108864 + 32768 + 1048576);         // 2 KB
    // xT (bf16 transposed x, 64MB) lives in d_out's first half; K6 overwrites all of d_out.
    unsigned short* xT = (unsigned short*)d_out;

    pack_kernel<<<dim3(1024), 256, 0, stream>>>(Wqkv, bqkv, Wp, Wv_bf, Wp_bf, bv);
    transpose_q_kernel<<<dim3(128, 16), 256, 0, stream>>>(x, Wqkv, xT, q);
    softmax_kernel<<<dim3(128), 256, 0, stream>>>(q, sT);
    xbar_kernel<<<dim3(16, 16), 256, 0, stream>>>(xT, sT, xbarP);
    ctx_kernel<<<dim3(128), 256, 0, stream>>>(xbarP, Wqkv, bqkv, ctx);
    gemm_kernel<0><<<dim3(32, 2, 16), 512, 0, stream>>>(Wv_bf, xT, bv, ctx, mT, nullptr);
    gemm_kernel<1><<<dim3(32, 2, 16), 512, 0, stream>>>(Wp_bf, mT, bp, nullptr, nullptr, outp);
}

// Round 10
// 222.566 us; speedup vs baseline: 1.5924x; 1.0373x over previous
//
#include <hip/hip_runtime.h>

// Problem constants: B=16, DIM(C)=512, N=4096, H=8, HD=64, QKV rows = 8*129 = 1032.
#define NB 16
#define NC 512
#define NN 4096
#define NH 8

typedef __attribute__((ext_vector_type(8))) __bf16 bf16x8;
typedef __attribute__((ext_vector_type(4))) float f32x4;

__device__ __forceinline__ unsigned short f2bf(float f) {
    union { float f; unsigned u; } x; x.f = f;
    unsigned r = x.u + 0x7FFF + ((x.u >> 16) & 1);   // round-to-nearest-even
    return (unsigned short)(r >> 16);
}
__device__ __forceinline__ float bits2f(unsigned u) {
    union { unsigned u; float f; } x; x.u = u; return x.f;
}

// async global->LDS 16B per lane; LDS dest must be wave-uniform base (HW adds lane*16).
__device__ __forceinline__ void async16(const void* g, const void* l) {
    __builtin_amdgcn_global_load_lds(
        (const __attribute__((address_space(1))) void*)g,
        (__attribute__((address_space(3))) void*)l, 16, 0, 0);
}

// K0: repack Wv rows (head-interleaved) + Wp to bf16, gather bv.
__global__ void pack_kernel(const float* __restrict__ Wqkv, const float* __restrict__ bqkv,
                            const float* __restrict__ Wp,
                            unsigned short* __restrict__ Wv_bf, unsigned short* __restrict__ Wp_bf,
                            float* __restrict__ bv) {
    int t = blockIdx.x * 256 + threadIdx.x;          // 0 .. 512*512-1
    int j = t >> 9, c = t & 511;
    int h = j >> 6, d = j & 63;
    Wv_bf[t] = f2bf(Wqkv[((size_t)h * 129 + 65 + d) * 512 + c]);
    Wp_bf[t] = f2bf(Wp[t]);
    if (t < 512) bv[t] = bqkv[(t >> 6) * 129 + 65 + (t & 63)];
}

// K1: fused transpose + q.  Block = (b, 32-n slab) x all 512 c.   (exact R2 version, 78us)
//   x [b][c][n] fp32  ->  xT [b][n][c] bf16
//   q [b][h][n] = sum_c Wq[h,c] * x[b,c,n]   (fp32 exact, bias dropped: softmax shift-inv)
__global__ __launch_bounds__(256) void transpose_q_kernel(
        const float* __restrict__ x, const float* __restrict__ Wqkv,
        unsigned short* __restrict__ xT, float* __restrict__ q) {
    __shared__ unsigned int tile[512 * 17];          // u32 = 2 packed bf16; pad 17 (coprime 32)
    __shared__ float Ws[8][512];
    __shared__ float qw[4][8][32];
    int b = blockIdx.y, n0 = blockIdx.x * 32;
    int t = threadIdx.x;                             // 256

    for (int i = t; i < 4096; i += 256)
        Ws[i >> 9][i & 511] = Wqkv[(size_t)(i >> 9) * (129 * 512) + (i & 511)];
    __syncthreads();

    // Phase 1: read x (coalesced float4 along n), pack->LDS, accumulate q partials.
    int k = t & 7;                                   // n-quad: n = 4k..4k+3
    int r0 = t >> 3;                                 // 0..31
    float accq[8][4];
#pragma unroll
    for (int h = 0; h < 8; h++)
#pragma unroll
        for (int j = 0; j < 4; j++) accq[h][j] = 0.f;
    const float* xp = x + (size_t)b * NC * NN + n0 + 4 * k;
#pragma unroll 4
    for (int p = 0; p < 16; p++) {
        int c = r0 + 32 * p;
        float4 v = *(const float4*)(xp + (size_t)c * NN);
        unsigned lo = (unsigned)f2bf(v.x) | ((unsigned)f2bf(v.y) << 16);
        unsigned hi = (unsigned)f2bf(v.z) | ((unsigned)f2bf(v.w) << 16);
        tile[c * 17 + 2 * k]     = lo;
        tile[c * 17 + 2 * k + 1] = hi;
#pragma unroll
        for (int h = 0; h < 8; h++) {
            float w = Ws[h][c];
            accq[h][0] += w * v.x;
            accq[h][1] += w * v.y;
            accq[h][2] += w * v.z;
            accq[h][3] += w * v.w;
        }
    }
    // q reduce: lanes sharing k (lane&7) differ in lane bits 3..5 = c-subset -> xor 8/16/32
    int lane = t & 63, wv = t >> 6;
#pragma unroll
    for (int h = 0; h < 8; h++)
#pragma unroll
        for (int j = 0; j < 4; j++) {
            float a = accq[h][j];
            a += __shfl_xor(a, 8);
            a += __shfl_xor(a, 16);
            a += __shfl_xor(a, 32);
            accq[h][j] = a;
        }
    if (lane < 8) {
#pragma unroll
        for (int h = 0; h < 8; h++)
#pragma unroll
            for (int j = 0; j < 4; j++) qw[wv][h][4 * lane + j] = accq[h][j];
    }
    __syncthreads();
    {
        int h = t >> 5, n = t & 31;
        q[((size_t)b * 8 + h) * NN + n0 + n] =
            qw[0][h][n] + qw[1][h][n] + qw[2][h][n] + qw[3][h][n];
    }

    // Phase 2: transpose out. lane = c (conflict-free: stride 17 u32), 128B-contig u16 stores.
    unsigned short* xb = xT + (size_t)b * NN * NC;
    for (int it = wv; it < 128; it += 4) {
        int cw = it >> 4, np = it & 15;
        int c = cw * 64 + lane;
        unsigned u = tile[c * 17 + np];
        int n = n0 + 2 * np;
        xb[(size_t)n * NC + c]       = (unsigned short)(u & 0xFFFFu);
        xb[(size_t)(n + 1) * NC + c] = (unsigned short)(u >> 16);
    }
}

// K2: softmax over N per (b,h); writes TRANSPOSED scores sT[b][n][h] (fp32).
__global__ void softmax_kernel(const float* __restrict__ q, float* __restrict__ sT) {
    int bh = blockIdx.x;                 // b*8+h
    int b = bh >> 3, h = bh & 7;
    int t = threadIdx.x;                 // 256
    __shared__ float red[8];
    const float* qp = q + (size_t)bh * NN;
    float v[16];
    float mx = -1e30f;
#pragma unroll
    for (int i = 0; i < 16; i++) { v[i] = qp[t + i * 256]; mx = fmaxf(mx, v[i]); }
#pragma unroll
    for (int o = 32; o; o >>= 1) mx = fmaxf(mx, __shfl_xor(mx, o));
    if ((t & 63) == 0) red[t >> 6] = mx;
    __syncthreads();
    mx = fmaxf(fmaxf(red[0], red[1]), fmaxf(red[2], red[3]));
    float s = 0.f;
#pragma unroll
    for (int i = 0; i < 16; i++) { v[i] = __expf(v[i] - mx); s += v[i]; }
#pragma unroll
    for (int o = 32; o; o >>= 1) s += __shfl_xor(s, o);
    __syncthreads();
    if ((t & 63) == 0) red[4 + (t >> 6)] = s;
    __syncthreads();
    float inv = 1.f / (red[4] + red[5] + red[6] + red[7]);
#pragma unroll
    for (int i = 0; i < 16; i++) {
        int n = t + i * 256;
        sT[((size_t)b * NN + n) * 8 + h] = v[i] * inv;
    }
}

// K3: partial xbar[sl64][b][h][c] = sum_{n in 64-slice} sT[b][n][h] * xT[b][n][c]
__global__ void xbar_kernel(const unsigned short* __restrict__ xT, const float* __restrict__ sT,
                            float* __restrict__ xbarP) {
    int b = blockIdx.y, sl = blockIdx.x;                 // 16 slices of 256 n
    int t = threadIdx.x;
    int g = __builtin_amdgcn_readfirstlane(t >> 6);      // wave id (uniform)
    int lane = t & 63;
    int c8 = lane * 8;
    int nbase = sl * 256 + g * 64;
    float acc[8][8];
#pragma unroll
    for (int h = 0; h < 8; h++)
#pragma unroll
        for (int c = 0; c < 8; c++) acc[h][c] = 0.f;
    const unsigned short* xp = xT + ((size_t)b * NN + nbase) * NC + c8;
    const float* sp = sT + ((size_t)b * NN + nbase) * 8;
    for (int i = 0; i < 64; i++) {
        uint4 xv = *(const uint4*)(xp + (size_t)i * NC);
        float xf[8];
        xf[0] = bits2f(xv.x << 16); xf[1] = bits2f(xv.x & 0xFFFF0000u);
        xf[2] = bits2f(xv.y << 16); xf[3] = bits2f(xv.y & 0xFFFF0000u);
        xf[4] = bits2f(xv.z << 16); xf[5] = bits2f(xv.z & 0xFFFF0000u);
        xf[6] = bits2f(xv.w << 16); xf[7] = bits2f(xv.w & 0xFFFF0000u);
#pragma unroll
        for (int h = 0; h < 8; h++) {
            float s = sp[i * 8 + h];
#pragma unroll
            for (int c = 0; c < 8; c++) acc[h][c] += s * xf[c];
        }
    }
#pragma unroll
    for (int h = 0; h < 8; h++) {
        float* dst = xbarP + (((size_t)(sl * 4 + g) * NB + b) * 8 + h) * NC + c8;
        f32x4 lo = {acc[h][0], acc[h][1], acc[h][2], acc[h][3]};
        f32x4 hi = {acc[h][4], acc[h][5], acc[h][6], acc[h][7]};
        *(f32x4*)(dst) = lo;
        *(f32x4*)(dst + 4) = hi;
    }
}

// K4: ctx[b][h*64+d] = Wk[h,d,:].xbar[b,h,:] + bk[h,d]   (sums 64 partial slices)
__global__ void ctx_kernel(const float* __restrict__ xbarP, const float* __restrict__ Wqkv,
                           const float* __restrict__ bqkv, float* __restrict__ ctx) {
    int bh = blockIdx.x; int b = bh >> 3, h = bh & 7;
    int t = threadIdx.x;                                    // 256
    __shared__ float xb[512];
    for (int i = t; i < 512; i += 256) {
        float s = 0.f;
        for (int sl = 0; sl < 64; sl++) s += xbarP[(((size_t)sl * NB + b) * 8 + h) * NC + i];
        xb[i] = s;
    }
    __syncthreads();
    int d = t >> 2, sub = t & 3;
    const float* wk = Wqkv + ((size_t)h * 129 + 1 + d) * 512;
    float acc = 0.f;
    for (int i = sub * 4; i < 512; i += 16) {
        float4 w = *(const float4*)(wk + i);
        acc += w.x * xb[i] + w.y * xb[i + 1] + w.z * xb[i + 2] + w.w * xb[i + 3];
    }
    acc += __shfl_xor(acc, 1);
    acc += __shfl_xor(acc, 2);
    if (sub == 0) ctx[(size_t)b * NC + h * 64 + d] = acc + bqkv[h * 129 + 1 + d];
}

// K5/K6: C[512 x 4096] = A[512x512] * B^T (B stored as [n][k] bf16 rows), per batch.
// m97-verified geometry: BM=BN=128, BK=64, 4 waves (2x2, 64x64 each), As/Bs 16KB linear,
// staging = 8x global_load_lds(16B) per thread per k-step, 2 barriers/step, 8 steps.
// MODE 0: epilogue relu(acc+bv)*ctx -> bf16, written TRANSPOSED mT[b][n][j].
// MODE 1: epilogue acc+bp -> fp32 out[b][o][n].
template <int MODE>
__global__ __launch_bounds__(256) void gemm_kernel(
    const unsigned short* __restrict__ A,     // [512][512] bf16 row-major
    const unsigned short* __restrict__ Bmat,  // [B][4096][512] bf16
    const float* __restrict__ bias,           // bv or bp
    const float* __restrict__ ctx,            // [B][512] (MODE 0)
    unsigned short* __restrict__ mT,          // MODE 0 output
    float* __restrict__ outp)                 // MODE 1 output
{
    __shared__ alignas(16) unsigned short As[128 * 64];   // [m][k] linear (async dest)
    __shared__ alignas(16) unsigned short Bs[128 * 64];   // [n][k] linear (async dest)
    int b = blockIdx.z;
    int m0 = blockIdx.y * 128, n0 = blockIdx.x * 128;
    int t = threadIdx.x;
    int lane = t & 63;
    int wid = t >> 6;                                     // 4 waves
    int wm = wid >> 1, wn = wid & 1;                      // 2x2 wave grid, 64x64 per wave

    const unsigned short* Bb = Bmat + ((size_t)b * NN + n0) * NC;

    // per-lane source offsets for async staging: 8 rows/instr, 16B per lane
    int srow = lane >> 3, sc8 = (lane & 7) * 8;

    f32x4 acc[4][4];
#pragma unroll
    for (int i = 0; i < 4; i++)
#pragma unroll
        for (int j = 0; j < 4; j++) { f32x4 z = {0.f, 0.f, 0.f, 0.f}; acc[i][j] = z; }

    for (int kk = 0; kk < 512; kk += 64) {
        // wave wid stages rows [wid*32, wid*32+32) of both As and Bs: 4 instr each.
#pragma unroll
        for (int u = 0; u < 4; u++) {
            int r = wid * 32 + u * 8;
            async16(A  + (size_t)(m0 + r + srow) * 512 + kk + sc8, As + (size_t)r * 64);
            async16(Bb + (size_t)(r + srow) * 512 + kk + sc8,      Bs + (size_t)r * 64);
        }
        __syncthreads();                                  // drains vmcnt before barrier
        bf16x8 af[2][4], bfr[2][4];
        int koff = (lane >> 4) * 8;
        int arow = wm * 64 + (lane & 15);
        int brow = wn * 64 + (lane & 15);
#pragma unroll
        for (int h = 0; h < 2; h++) {
#pragma unroll
            for (int i = 0; i < 4; i++)
                af[h][i]  = *(const bf16x8*)(As + (size_t)(arow + i * 16) * 64 + h * 32 + koff);
#pragma unroll
            for (int j = 0; j < 4; j++)
                bfr[h][j] = *(const bf16x8*)(Bs + (size_t)(brow + j * 16) * 64 + h * 32 + koff);
        }
#pragma unroll
        for (int i = 0; i < 4; i++)
#pragma unroll
            for (int j = 0; j < 4; j++) {
                acc[i][j] = __builtin_amdgcn_mfma_f32_16x16x32_bf16(af[0][i], bfr[0][j], acc[i][j], 0, 0, 0);
                acc[i][j] = __builtin_amdgcn_mfma_f32_16x16x32_bf16(af[1][i], bfr[1][j], acc[i][j], 0, 0, 0);
            }
        __syncthreads();
    }

    // epilogue; D frag: n-col = lane&15, m-row = (lane>>4)*4 + reg
    int g = lane >> 4, col = lane & 15;
#pragma unroll
    for (int i = 0; i < 4; i++) {
        int j0 = m0 + wm * 64 + i * 16 + g * 4;           // 4 consecutive output rows
        if (MODE == 0) {
            float4 bv4 = *(const float4*)(bias + j0);
            float4 cx4 = *(const float4*)(ctx + (size_t)b * NC + j0);
#pragma unroll
            for (int j = 0; j < 4; j++) {
                int n = n0 + wn * 64 + j * 16 + col;
                f32x4 a = acc[i][j];
                unsigned short h0 = f2bf(fmaxf(a[0] + bv4.x, 0.f) * cx4.x);
                unsigned short h1 = f2bf(fmaxf(a[1] + bv4.y, 0.f) * cx4.y);
                unsigned short h2 = f2bf(fmaxf(a[2] + bv4.z, 0.f) * cx4.z);
                unsigned short h3 = f2bf(fmaxf(a[3] + bv4.w, 0.f) * cx4.w);
                uint2 pk;
                pk.x = (unsigned)h0 | ((unsigned)h1 << 16);
                pk.y = (unsigned)h2 | ((unsigned)h3 << 16);
                *(uint2*)(mT + ((size_t)b * NN + n) * NC + j0) = pk;
            }
        } else {
            float4 bp4 = *(const float4*)(bias + j0);
#pragma unroll
            for (int j = 0; j < 4; j++) {
                int n = n0 + wn * 64 + j * 16 + col;
                f32x4 a = acc[i][j];
                float* op = outp + (size_t)b * NC * NN + (size_t)j0 * NN + n;
                op[0]              = a[0] + bp4.x;
                op[NN]             = a[1] + bp4.y;
                op[2 * (size_t)NN] = a[2] + bp4.z;
                op[3 * (size_t)NN] = a[3] + bp4.w;
            }
        }
    }
}

extern "C" void kernel_launch(void* const* d_in, const int* in_sizes, int n_in,
                              void* d_out, int out_size, void* d_ws, size_t ws_size,
                              hipStream_t stream) {
    const float* x    = (const float*)d_in[0];
    const float* Wqkv = (const float*)d_in[1];
    const float* bqkv = (const float*)d_in[2];
    const float* Wp   = (const float*)d_in[3];
    const float* bp   = (const float*)d_in[4];
    float* outp = (float*)d_out;

    // ws layout. mT occupies [0, 64MB). sT/q/xbarP overlap mT's range but are
    // fully consumed (K1..K4) before K5 writes mT. ctx/Wv/Wp/bv live past 64MB.
    char* ws = (char*)d_ws;
    unsigned short* mT = (unsigned short*)ws;                         // 64 MB
    float* sT    = (float*)(ws + 2097152);                            // [2MB,4MB)
    float* q     = (float*)(ws + 4194304);                            // [4MB,6MB)
    float* xbarP = (float*)(ws + 20971520);                           // [20MB,36MB)
    float* ctx   = (float*)(ws + 67108864);                           // 32 KB
    unsigned short* Wv_bf = (unsigned short*)(ws + 67108864 + 32768);            // 512 KB
    unsigned short* Wp_bf = (unsigned short*)(ws + 67108864 + 32768 + 524288);   // 512 KB
    float* bv    = (float*)(ws + 67108864 + 32768 + 1048576);         // 2 KB
    // xT (bf16 transposed x, 64MB) lives in d_out's first half; K6 overwrites all of d_out.
    unsigned short* xT = (unsigned short*)d_out;

    pack_kernel<<<dim3(1024), 256, 0, stream>>>(Wqkv, bqkv, Wp, Wv_bf, Wp_bf, bv);
    transpose_q_kernel<<<dim3(128, 16), 256, 0, stream>>>(x, Wqkv, xT, q);
    softmax_kernel<<<dim3(128), 256, 0, stream>>>(q, sT);
    xbar_kernel<<<dim3(16, 16), 256, 0, stream>>>(xT, sT, xbarP);
    ctx_kernel<<<dim3(128), 256, 0, stream>>>(xbarP, Wqkv, bqkv, ctx);
    gemm_kernel<0><<<dim3(32, 4, 16), 256, 0, stream>>>(Wv_bf, xT, bv, ctx, mT, nullptr);
    gemm_kernel<1><<<dim3(32, 4, 16), 256, 0, stream>>>(Wp_bf, mT, bp, nullptr, nullptr, outp);
}